// Round 1
// baseline (6978.045 us; speedup 1.0000x reference)
//
#include <hip/hip_runtime.h>
#include <hip/hip_bf16.h>
#include <math.h>

#define Bsz 4096
#define Tt 80
#define Vv 10000
#define Ee 100
#define Uu 512

typedef __attribute__((ext_vector_type(8))) short short8;
typedef __attribute__((ext_vector_type(4))) float f32x4;

__device__ __forceinline__ unsigned short f2bf(float f) {
    union { float f; unsigned u; } x{f};
    unsigned u = x.u;
    unsigned r = (u + 0x7fffu + ((u >> 16) & 1u)) >> 16;
    return (unsigned short)r;
}

// P1: embW0[v][u] = sum_e emb[v][e]*W0[e][u] + b0[u]   (fp32, exact input term)
__global__ __launch_bounds__(512) void k_embw0(const float* __restrict__ emb,
                                               const float* __restrict__ W0,
                                               const float* __restrict__ b0,
                                               float* __restrict__ embW0) {
    __shared__ float semb[4][Ee];
    int v0 = blockIdx.x * 4;
    int tid = threadIdx.x;
    if (tid < 4 * Ee) semb[tid / Ee][tid % Ee] = emb[(v0 + tid / Ee) * Ee + tid % Ee];
    __syncthreads();
    float b = b0[tid];
    for (int vl = 0; vl < 4; ++vl) {
        float a = 0.f;
        #pragma unroll 4
        for (int e = 0; e < Ee; ++e) a += semb[vl][e] * W0[e * Uu + tid];
        embW0[(v0 + vl) * Uu + tid] = a + b;
    }
}

// P2: pack U0,W1,U1 (fp32 row-major [512][512]) into bf16 MFMA B-fragment order:
// flat[( (ntg*16 + ks)*64 + lane )*8 + j] = M[ks*32 + 8*(lane>>4) + j][ntg*16 + (lane&15)]
__global__ __launch_bounds__(256) void k_pack(const float* __restrict__ U0,
                                              const float* __restrict__ W1,
                                              const float* __restrict__ U1,
                                              unsigned short* __restrict__ pU0,
                                              unsigned short* __restrict__ pW1,
                                              unsigned short* __restrict__ pU1) {
    int gid = blockIdx.x * 256 + threadIdx.x;   // 0 .. 98303 (3 * 512 frags * 64 lanes)
    int m = gid >> 15;
    int rem = gid & 32767;
    int frag = rem >> 6;          // ntg*16 + ks
    int lane = rem & 63;
    int ntg = frag >> 4, ks = frag & 15;
    const float* src = (m == 0) ? U0 : (m == 1) ? W1 : U1;
    unsigned short* dst = (m == 0) ? pU0 : (m == 1) ? pW1 : pU1;
    int row0 = ks * 32 + (lane >> 4) * 8;
    int col = ntg * 16 + (lane & 15);
    short8 val;
    #pragma unroll
    for (int j = 0; j < 8; ++j) val[j] = (short)f2bf(src[(row0 + j) * Uu + col]);
    *(short8*)(dst + (size_t)rem * 8) = val;
}

// Main: 256 blocks x 16 batch rows, 8 waves (each owns 64 output cols = 4 n-tiles).
// Time loop inside the block; h0/h1 as bf16 in LDS with XOR swizzle.
__global__ __launch_bounds__(512) void k_rnn(const int* __restrict__ tokens,
                                             const float* __restrict__ embW0,
                                             const unsigned short* __restrict__ pU0,
                                             const unsigned short* __restrict__ pW1,
                                             const unsigned short* __restrict__ pU1,
                                             const float* __restrict__ b1,
                                             const float* __restrict__ Wout,
                                             const float* __restrict__ bout,
                                             float* __restrict__ out) {
    __shared__ __align__(16) char smem[32768];
    char* h0b = smem;                 // bf16 [16][512] swizzled, 16KB
    char* h1b = smem + 16384;         // bf16 [16][512] swizzled, 16KB
    float* finalb = (float*)smem;     // fp32 [16][512] (reused after last step)

    int tid = threadIdx.x;
    int lane = tid & 63;
    int wv = tid >> 6;                // 0..7
    int bbase = blockIdx.x * 16;
    int q = lane >> 4;
    int ln = lane & 15;
    int colbase = wv * 64 + ln;

    // zero h buffers
    {
        uint4 z = {0u, 0u, 0u, 0u};
        for (int i = tid; i < 2048; i += 512) ((uint4*)smem)[i] = z;
    }

    float b1c[4];
    #pragma unroll
    for (int n = 0; n < 4; ++n) b1c[n] = b1[colbase + n * 16];

    const short8* pb0 = (const short8*)pU0 + lane;
    const short8* pbW = (const short8*)pW1 + lane;
    const short8* pbU = (const short8*)pU1 + lane;

    int mrow[4];
    #pragma unroll
    for (int r = 0; r < 4; ++r) mrow[r] = q * 4 + r;

    __syncthreads();

    for (int t = 0; t < Tt; ++t) {
        // ---------- layer 0: h0' = tanh(gather(embW0) + h0 @ U0) ----------
        int tok[4];
        #pragma unroll
        for (int r = 0; r < 4; ++r) tok[r] = tokens[(bbase + mrow[r]) * Tt + t];
        f32x4 acc0[4];
        #pragma unroll
        for (int n = 0; n < 4; ++n)
            #pragma unroll
            for (int r = 0; r < 4; ++r)
                acc0[n][r] = embW0[tok[r] * Uu + colbase + n * 16];
        #pragma unroll
        for (int ks = 0; ks < 16; ++ks) {
            int byteA = (ln * 1024 + ks * 64 + q * 16) ^ ((ln & 7) << 4);
            short8 a = *(const short8*)(h0b + byteA);
            #pragma unroll
            for (int n = 0; n < 4; ++n) {
                short8 b = pb0[((wv * 4 + n) * 16 + ks) * 64];
                acc0[n] = __builtin_amdgcn_mfma_f32_16x16x32_bf16(a, b, acc0[n], 0, 0, 0);
            }
        }
        float th0[4][4];
        #pragma unroll
        for (int n = 0; n < 4; ++n)
            #pragma unroll
            for (int r = 0; r < 4; ++r) th0[n][r] = tanhf(acc0[n][r]);

        __syncthreads();   // [A] all reads of old h0 done
        #pragma unroll
        for (int n = 0; n < 4; ++n)
            #pragma unroll
            for (int r = 0; r < 4; ++r) {
                int m = mrow[r];
                int col = colbase + n * 16;
                int byte = (m * 1024 + col * 2) ^ ((m & 7) << 4);
                *(unsigned short*)(h0b + byte) = f2bf(th0[n][r]);
            }
        __syncthreads();   // [B] h0_new visible

        // ---------- layer 1: h1' = tanh(b1 + h0' @ W1 + h1 @ U1) ----------
        f32x4 acc1[4];
        #pragma unroll
        for (int n = 0; n < 4; ++n) {
            acc1[n][0] = b1c[n]; acc1[n][1] = b1c[n];
            acc1[n][2] = b1c[n]; acc1[n][3] = b1c[n];
        }
        #pragma unroll
        for (int ks = 0; ks < 16; ++ks) {
            int byteA = (ln * 1024 + ks * 64 + q * 16) ^ ((ln & 7) << 4);
            short8 aw = *(const short8*)(h0b + byteA);
            short8 au = *(const short8*)(h1b + byteA);
            #pragma unroll
            for (int n = 0; n < 4; ++n) {
                int f = ((wv * 4 + n) * 16 + ks) * 64;
                acc1[n] = __builtin_amdgcn_mfma_f32_16x16x32_bf16(aw, pbW[f], acc1[n], 0, 0, 0);
                acc1[n] = __builtin_amdgcn_mfma_f32_16x16x32_bf16(au, pbU[f], acc1[n], 0, 0, 0);
            }
        }
        float th1[4][4];
        #pragma unroll
        for (int n = 0; n < 4; ++n)
            #pragma unroll
            for (int r = 0; r < 4; ++r) th1[n][r] = tanhf(acc1[n][r]);

        __syncthreads();   // [C] all reads of old h1 done
        if (t < Tt - 1) {
            #pragma unroll
            for (int n = 0; n < 4; ++n)
                #pragma unroll
                for (int r = 0; r < 4; ++r) {
                    int m = mrow[r];
                    int col = colbase + n * 16;
                    int byte = (m * 1024 + col * 2) ^ ((m & 7) << 4);
                    *(unsigned short*)(h1b + byte) = f2bf(th1[n][r]);
                }
        } else {
            #pragma unroll
            for (int n = 0; n < 4; ++n)
                #pragma unroll
                for (int r = 0; r < 4; ++r)
                    finalb[mrow[r] * Uu + colbase + n * 16] = th1[n][r];
        }
    }
    __syncthreads();

    // output: out[b] = sigmoid(h1[b,:] @ Wout + bout); wave wv -> rows wv, wv+8
    #pragma unroll
    for (int rr = 0; rr < 2; ++rr) {
        int row = wv + rr * 8;
        float s = 0.f;
        #pragma unroll
        for (int j = 0; j < 8; ++j)
            s += finalb[row * Uu + lane * 8 + j] * Wout[lane * 8 + j];
        #pragma unroll
        for (int off = 32; off; off >>= 1) s += __shfl_xor(s, off);
        if (lane == 0) out[bbase + row] = 1.f / (1.f + expf(-(s + bout[0])));
    }
}

extern "C" void kernel_launch(void* const* d_in, const int* in_sizes, int n_in,
                              void* d_out, int out_size, void* d_ws, size_t ws_size,
                              hipStream_t stream) {
    const int*   tokens = (const int*)d_in[0];
    const float* emb    = (const float*)d_in[1];
    const float* W0     = (const float*)d_in[2];
    const float* U0     = (const float*)d_in[3];
    const float* b0     = (const float*)d_in[4];
    const float* W1     = (const float*)d_in[5];
    const float* U1     = (const float*)d_in[6];
    const float* b1     = (const float*)d_in[7];
    const float* Wout   = (const float*)d_in[8];
    const float* bout   = (const float*)d_in[9];
    float* outp = (float*)d_out;

    char* ws = (char*)d_ws;
    float* embW0 = (float*)ws;                                   // 20,480,000 B
    unsigned short* pU0 = (unsigned short*)(ws + 20480000);      // 512KB each
    unsigned short* pW1 = pU0 + 262144;
    unsigned short* pU1 = pW1 + 262144;

    hipLaunchKernelGGL(k_embw0, dim3(Vv / 4), dim3(512), 0, stream, emb, W0, b0, embW0);
    hipLaunchKernelGGL(k_pack, dim3(384), dim3(256), 0, stream, U0, W1, U1, pU0, pW1, pU1);
    hipLaunchKernelGGL(k_rnn, dim3(256), dim3(512), 0, stream,
                       tokens, embW0, pU0, pW1, pU1, b1, Wout, bout, outp);
}

// Round 2
// 6743.345 us; speedup vs baseline: 1.0348x; 1.0348x over previous
//
#include <hip/hip_runtime.h>
#include <hip/hip_bf16.h>
#include <math.h>

#define Bsz 4096
#define Tt 80
#define Vv 10000
#define Ee 100
#define Uu 512

typedef __attribute__((ext_vector_type(8))) short short8;
typedef __attribute__((ext_vector_type(4))) float f32x4;

__device__ __forceinline__ unsigned short f2bf(float f) {
    union { float f; unsigned u; } x{f};
    unsigned u = x.u;
    unsigned r = (u + 0x7fffu + ((u >> 16) & 1u)) >> 16;
    return (unsigned short)r;
}

// P1: embW0[v][u] = sum_e emb[v][e]*W0[e][u] + b0[u]   (fp32, exact input term)
__global__ __launch_bounds__(512) void k_embw0(const float* __restrict__ emb,
                                               const float* __restrict__ W0,
                                               const float* __restrict__ b0,
                                               float* __restrict__ embW0) {
    __shared__ float semb[4][Ee];
    int v0 = blockIdx.x * 4;
    int tid = threadIdx.x;
    if (tid < 4 * Ee) semb[tid / Ee][tid % Ee] = emb[(v0 + tid / Ee) * Ee + tid % Ee];
    __syncthreads();
    float b = b0[tid];
    for (int vl = 0; vl < 4; ++vl) {
        float a = 0.f;
        #pragma unroll 4
        for (int e = 0; e < Ee; ++e) a += semb[vl][e] * W0[e * Uu + tid];
        embW0[(v0 + vl) * Uu + tid] = a + b;
    }
}

// P2: pack U0,W1,U1 (fp32 row-major [512][512]) into bf16 MFMA B-fragment order:
// flat[( (ntg*16 + ks)*64 + lane )*8 + j] = M[ks*32 + 8*(lane>>4) + j][ntg*16 + (lane&15)]
__global__ __launch_bounds__(256) void k_pack(const float* __restrict__ U0,
                                              const float* __restrict__ W1,
                                              const float* __restrict__ U1,
                                              unsigned short* __restrict__ pU0,
                                              unsigned short* __restrict__ pW1,
                                              unsigned short* __restrict__ pU1) {
    int gid = blockIdx.x * 256 + threadIdx.x;   // 0 .. 98303 (3 * 512 frags * 64 lanes)
    int m = gid >> 15;
    int rem = gid & 32767;
    int frag = rem >> 6;          // ntg*16 + ks
    int lane = rem & 63;
    int ntg = frag >> 4, ks = frag & 15;
    const float* src = (m == 0) ? U0 : (m == 1) ? W1 : U1;
    unsigned short* dst = (m == 0) ? pU0 : (m == 1) ? pW1 : pU1;
    int row0 = ks * 32 + (lane >> 4) * 8;
    int col = ntg * 16 + (lane & 15);
    short8 val;
    #pragma unroll
    for (int j = 0; j < 8; ++j) val[j] = (short)f2bf(src[(row0 + j) * Uu + col]);
    *(short8*)(dst + (size_t)rem * 8) = val;
}

// Main: 256 blocks x 16 batch rows, 8 waves (each owns 64 output cols = 4 n-tiles).
// Time loop inside the block; h0/h1 as bf16 in LDS with XOR swizzle.
// embW0 gather uses NON-TEMPORAL loads so the transient 20MB-table stream does
// not evict the L2-resident 1.5MB weight working set (round-1 FETCH=13.3GB fix).
__global__ __launch_bounds__(512) void k_rnn(const int* __restrict__ tokens,
                                             const float* __restrict__ embW0,
                                             const unsigned short* __restrict__ pU0,
                                             const unsigned short* __restrict__ pW1,
                                             const unsigned short* __restrict__ pU1,
                                             const float* __restrict__ b1,
                                             const float* __restrict__ Wout,
                                             const float* __restrict__ bout,
                                             float* __restrict__ out) {
    __shared__ __align__(16) char smem[32768 + 16 * Tt * 4];
    char* h0b = smem;                 // bf16 [16][512] swizzled, 16KB
    char* h1b = smem + 16384;         // bf16 [16][512] swizzled, 16KB
    float* finalb = (float*)smem;     // fp32 [16][512] (reused after last step)
    int* stok = (int*)(smem + 32768); // [16][80] token slab for this block

    int tid = threadIdx.x;
    int lane = tid & 63;
    int wv = tid >> 6;                // 0..7
    int bbase = blockIdx.x * 16;
    int q = lane >> 4;
    int ln = lane & 15;
    int colbase = wv * 64 + ln;

    // zero h buffers
    {
        uint4 z = {0u, 0u, 0u, 0u};
        for (int i = tid; i < 2048; i += 512) ((uint4*)smem)[i] = z;
    }
    // stage tokens (contiguous rows for this block)
    for (int i = tid; i < 16 * Tt; i += 512) stok[i] = tokens[bbase * Tt + i];

    float b1c[4];
    #pragma unroll
    for (int n = 0; n < 4; ++n) b1c[n] = b1[colbase + n * 16];

    const short8* pb0 = (const short8*)pU0 + lane;
    const short8* pbW = (const short8*)pW1 + lane;
    const short8* pbU = (const short8*)pU1 + lane;

    int mrow[4];
    #pragma unroll
    for (int r = 0; r < 4; ++r) mrow[r] = q * 4 + r;

    __syncthreads();

    for (int t = 0; t < Tt; ++t) {
        // ---------- layer 0: h0' = tanh(gather(embW0) + h0 @ U0) ----------
        int tok[4];
        #pragma unroll
        for (int r = 0; r < 4; ++r) tok[r] = stok[mrow[r] * Tt + t];
        f32x4 acc0[4];
        #pragma unroll
        for (int n = 0; n < 4; ++n)
            #pragma unroll
            for (int r = 0; r < 4; ++r)
                acc0[n][r] = __builtin_nontemporal_load(&embW0[tok[r] * Uu + colbase + n * 16]);
        #pragma unroll
        for (int ks = 0; ks < 16; ++ks) {
            int byteA = (ln * 1024 + ks * 64 + q * 16) ^ ((ln & 7) << 4);
            short8 a = *(const short8*)(h0b + byteA);
            #pragma unroll
            for (int n = 0; n < 4; ++n) {
                short8 b = pb0[((wv * 4 + n) * 16 + ks) * 64];
                acc0[n] = __builtin_amdgcn_mfma_f32_16x16x32_bf16(a, b, acc0[n], 0, 0, 0);
            }
        }
        float th0[4][4];
        #pragma unroll
        for (int n = 0; n < 4; ++n)
            #pragma unroll
            for (int r = 0; r < 4; ++r) th0[n][r] = tanhf(acc0[n][r]);

        __syncthreads();   // [A] all reads of old h0 done
        #pragma unroll
        for (int n = 0; n < 4; ++n)
            #pragma unroll
            for (int r = 0; r < 4; ++r) {
                int m = mrow[r];
                int col = colbase + n * 16;
                int byte = (m * 1024 + col * 2) ^ ((m & 7) << 4);
                *(unsigned short*)(h0b + byte) = f2bf(th0[n][r]);
            }
        __syncthreads();   // [B] h0_new visible

        // ---------- layer 1: h1' = tanh(b1 + h0' @ W1 + h1 @ U1) ----------
        f32x4 acc1[4];
        #pragma unroll
        for (int n = 0; n < 4; ++n) {
            acc1[n][0] = b1c[n]; acc1[n][1] = b1c[n];
            acc1[n][2] = b1c[n]; acc1[n][3] = b1c[n];
        }
        #pragma unroll
        for (int ks = 0; ks < 16; ++ks) {
            int byteA = (ln * 1024 + ks * 64 + q * 16) ^ ((ln & 7) << 4);
            short8 aw = *(const short8*)(h0b + byteA);
            short8 au = *(const short8*)(h1b + byteA);
            #pragma unroll
            for (int n = 0; n < 4; ++n) {
                int f = ((wv * 4 + n) * 16 + ks) * 64;
                acc1[n] = __builtin_amdgcn_mfma_f32_16x16x32_bf16(aw, pbW[f], acc1[n], 0, 0, 0);
                acc1[n] = __builtin_amdgcn_mfma_f32_16x16x32_bf16(au, pbU[f], acc1[n], 0, 0, 0);
            }
        }
        float th1[4][4];
        #pragma unroll
        for (int n = 0; n < 4; ++n)
            #pragma unroll
            for (int r = 0; r < 4; ++r) th1[n][r] = tanhf(acc1[n][r]);

        __syncthreads();   // [C] all reads of old h1 done
        if (t < Tt - 1) {
            #pragma unroll
            for (int n = 0; n < 4; ++n)
                #pragma unroll
                for (int r = 0; r < 4; ++r) {
                    int m = mrow[r];
                    int col = colbase + n * 16;
                    int byte = (m * 1024 + col * 2) ^ ((m & 7) << 4);
                    *(unsigned short*)(h1b + byte) = f2bf(th1[n][r]);
                }
        } else {
            #pragma unroll
            for (int n = 0; n < 4; ++n)
                #pragma unroll
                for (int r = 0; r < 4; ++r)
                    finalb[mrow[r] * Uu + colbase + n * 16] = th1[n][r];
        }
    }
    __syncthreads();

    // output: out[b] = sigmoid(h1[b,:] @ Wout + bout); wave wv -> rows wv, wv+8
    #pragma unroll
    for (int rr = 0; rr < 2; ++rr) {
        int row = wv + rr * 8;
        float s = 0.f;
        #pragma unroll
        for (int j = 0; j < 8; ++j)
            s += finalb[row * Uu + lane * 8 + j] * Wout[lane * 8 + j];
        #pragma unroll
        for (int off = 32; off; off >>= 1) s += __shfl_xor(s, off);
        if (lane == 0) out[bbase + row] = 1.f / (1.f + expf(-(s + bout[0])));
    }
}

extern "C" void kernel_launch(void* const* d_in, const int* in_sizes, int n_in,
                              void* d_out, int out_size, void* d_ws, size_t ws_size,
                              hipStream_t stream) {
    const int*   tokens = (const int*)d_in[0];
    const float* emb    = (const float*)d_in[1];
    const float* W0     = (const float*)d_in[2];
    const float* U0     = (const float*)d_in[3];
    const float* b0     = (const float*)d_in[4];
    const float* W1     = (const float*)d_in[5];
    const float* U1     = (const float*)d_in[6];
    const float* b1     = (const float*)d_in[7];
    const float* Wout   = (const float*)d_in[8];
    const float* bout   = (const float*)d_in[9];
    float* outp = (float*)d_out;

    char* ws = (char*)d_ws;
    float* embW0 = (float*)ws;                                   // 20,480,000 B
    unsigned short* pU0 = (unsigned short*)(ws + 20480000);      // 512KB each
    unsigned short* pW1 = pU0 + 262144;
    unsigned short* pU1 = pW1 + 262144;

    hipLaunchKernelGGL(k_embw0, dim3(Vv / 4), dim3(512), 0, stream, emb, W0, b0, embW0);
    hipLaunchKernelGGL(k_pack, dim3(384), dim3(256), 0, stream, U0, W1, U1, pU0, pW1, pU1);
    hipLaunchKernelGGL(k_rnn, dim3(256), dim3(512), 0, stream,
                       tokens, embW0, pU0, pW1, pU1, b1, Wout, bout, outp);
}

// Round 3
// 5544.320 us; speedup vs baseline: 1.2586x; 1.2163x over previous
//
#include <hip/hip_runtime.h>
#include <hip/hip_bf16.h>
#include <math.h>

#define Tt 80
#define Vv 10000
#define Ee 100
#define Uu 512
#define ROWS 32
#define NBLK 128
#define SLICE_B 32768
#define NSLICE 48

typedef __attribute__((ext_vector_type(8))) short short8;
typedef __attribute__((ext_vector_type(4))) float f32x4;

__device__ __forceinline__ unsigned short f2bf(float f) {
    union { float f; unsigned u; } x{f};
    unsigned u = x.u;
    return (unsigned short)((u + 0x7fffu + ((u >> 16) & 1u)) >> 16);
}

// ---------------- P1: embW0 = emb@W0 + b0 (fp32) ----------------
__global__ __launch_bounds__(512) void k_embw0(const float* __restrict__ emb,
                                               const float* __restrict__ W0,
                                               const float* __restrict__ b0,
                                               float* __restrict__ embW0) {
    __shared__ float semb[4][Ee];
    int v0 = blockIdx.x * 4;
    int tid = threadIdx.x;
    if (tid < 4 * Ee) semb[tid / Ee][tid % Ee] = emb[(v0 + tid / Ee) * Ee + tid % Ee];
    __syncthreads();
    float b = b0[tid];
    for (int vl = 0; vl < 4; ++vl) {
        float a = 0.f;
        #pragma unroll 4
        for (int e = 0; e < Ee; ++e) a += semb[vl][e] * W0[e * Uu + tid];
        embW0[(v0 + vl) * Uu + tid] = a + b;
    }
}

// ---------------- P2: pack weights into 48 contiguous 32KB K-slices ----------------
// Slice S<16: U0 ks=S.  S>=16: s2=S-16, ks=s2>>1, mat = (s2&1)? U1 : W1.
// Within slice: [(ntg*64 + lane)*8 + j] = M[ks*32 + 8*(lane>>4) + j][ntg*16 + (lane&15)]
__global__ __launch_bounds__(256) void k_pack(const float* __restrict__ U0,
                                              const float* __restrict__ W1,
                                              const float* __restrict__ U1,
                                              unsigned short* __restrict__ pW) {
    int gid = blockIdx.x * 256 + threadIdx.x;   // 0 .. 98303 (48 slices * 32 ntg * 64 lanes)
    int S = gid >> 11;
    int ntg = (gid >> 6) & 31;
    int lane = gid & 63;
    const float* src;
    int ks;
    if (S < 16) { src = U0; ks = S; }
    else { int s2 = S - 16; ks = s2 >> 1; src = (s2 & 1) ? U1 : W1; }
    int row0 = ks * 32 + (lane >> 4) * 8;
    int col = ntg * 16 + (lane & 15);
    short8 v;
    #pragma unroll
    for (int j = 0; j < 8; ++j) v[j] = (short)f2bf(src[(row0 + j) * Uu + col]);
    *(short8*)(pW + (size_t)gid * 8) = v;
}

// ---------------- main RNN kernel ----------------
__device__ __forceinline__ void stage4(const char* gs, char* ld, int wv, int lane) {
    #pragma unroll
    for (int k2 = 0; k2 < 4; ++k2)
        __builtin_amdgcn_global_load_lds(
            (const __attribute__((address_space(1))) void*)(gs + (wv * 4 + k2) * 1024 + lane * 16),
            (__attribute__((address_space(3))) void*)(ld + (wv * 4 + k2) * 1024),
            16, 0, 0);
}

#define VM_SYNC() do { asm volatile("s_waitcnt vmcnt(4)" ::: "memory"); \
    __builtin_amdgcn_sched_barrier(0); __builtin_amdgcn_s_barrier(); \
    __builtin_amdgcn_sched_barrier(0); } while (0)
#define LG_SYNC() do { asm volatile("s_waitcnt lgkmcnt(0)" ::: "memory"); \
    __builtin_amdgcn_sched_barrier(0); __builtin_amdgcn_s_barrier(); \
    __builtin_amdgcn_sched_barrier(0); } while (0)

__global__ __launch_bounds__(512) void k_rnn(const int* __restrict__ tokens,
                                             const float* __restrict__ embW0,
                                             const unsigned short* __restrict__ pWu,
                                             const float* __restrict__ b1,
                                             const float* __restrict__ Wout,
                                             const float* __restrict__ bout,
                                             float* __restrict__ out) {
    __shared__ __align__(16) char smem[131072];
    char* h0b = smem;                  // bf16 [32][512] swizzled, 32KB
    char* h1b = smem + 32768;          // bf16 [32][512] swizzled, 32KB
    char* ring = smem + 65536;         // 2 x 32KB staging ring
    float* finalb = (float*)ring;      // fp32 [32][512] overlay for epilogue

    const int tid = threadIdx.x;
    const int lane = tid & 63;
    const int wv = tid >> 6;           // 0..7, owns cols wv*64 .. wv*64+63 (ntg wv*4..wv*4+3)
    const int q = lane >> 4;
    const int ln = lane & 15;
    const int bbase = blockIdx.x * ROWS;
    const int swz = (ln & 7) << 4;
    const char* pW = (const char*)pWu;

    // zero h buffers (64KB)
    {
        uint4 z = {0u, 0u, 0u, 0u};
        for (int i = tid; i < 4096; i += 512) ((uint4*)smem)[i] = z;
    }
    __syncthreads();   // before any staging is issued (its vmcnt(0) drain is harmless here)

    // prologue: stage slice 0 into ring slot 0
    int cur = 0;
    stage4(pW, ring, wv, lane);
    cur = 1;

    float b1c[4];
    #pragma unroll
    for (int n = 0; n < 4; ++n) b1c[n] = b1[wv * 64 + n * 16 + ln];
    float wout[8];
    #pragma unroll
    for (int j = 0; j < 8; ++j) wout[j] = Wout[lane * 8 + j];
    float boutv = bout[0];

    f32x4 th1[2][4];   // persists across steps

    for (int t = 0; t < Tt; ++t) {
        // gather input term: acc0 = embW0[token] (fp32, exact)
        f32x4 acc0[2][4];
        #pragma unroll
        for (int m = 0; m < 2; ++m)
            #pragma unroll
            for (int r = 0; r < 4; ++r) {
                int tk = tokens[(bbase + m * 16 + q * 4 + r) * Tt + t];
                #pragma unroll
                for (int n = 0; n < 4; ++n)
                    acc0[m][n][r] = __builtin_nontemporal_load(
                        &embW0[tk * Uu + wv * 64 + n * 16 + ln]);
            }

        // ---------------- layer 0: 16 phases (slices 0..15 = U0) ----------------
        #pragma unroll
        for (int ks = 0; ks < 16; ++ks) {
            stage4(pW + (size_t)cur * SLICE_B, ring + (cur & 1) * SLICE_B, wv, lane);
            cur = (cur == NSLICE - 1) ? 0 : cur + 1;
            VM_SYNC();
            if (ks == 0 && t > 0) {
                // write previous step's th1 into h1b (all waves past last U1 read)
                #pragma unroll
                for (int m = 0; m < 2; ++m)
                    #pragma unroll
                    for (int n = 0; n < 4; ++n)
                        #pragma unroll
                        for (int r = 0; r < 4; ++r) {
                            int row = m * 16 + q * 4 + r;
                            int col = wv * 64 + n * 16 + ln;
                            *(unsigned short*)(h1b + ((row * 1024 + col * 2) ^ ((row & 7) << 4)))
                                = f2bf(th1[m][n][r]);
                        }
                LG_SYNC();
            }
            char* rs = ring + (ks & 1) * SLICE_B;
            short8 bfr[4];
            #pragma unroll
            for (int n = 0; n < 4; ++n)
                bfr[n] = *(const short8*)(rs + ((wv * 4 + n) * 64 + lane) * 16);
            #pragma unroll
            for (int m = 0; m < 2; ++m) {
                short8 afr = *(const short8*)(h0b + (((m * 16 + ln) * 1024 + ks * 64 + q * 16) ^ swz));
                #pragma unroll
                for (int n = 0; n < 4; ++n)
                    acc0[m][n] = __builtin_amdgcn_mfma_f32_16x16x32_bf16(afr, bfr[n], acc0[m][n], 0, 0, 0);
            }
        }

        f32x4 th0[2][4];
        #pragma unroll
        for (int m = 0; m < 2; ++m)
            #pragma unroll
            for (int n = 0; n < 4; ++n)
                #pragma unroll
                for (int r = 0; r < 4; ++r) th0[m][n][r] = tanhf(acc0[m][n][r]);

        // ---------------- layer 1: 32 phases (slices 16..47 = W1/U1 interleaved) ----------------
        f32x4 acc1[2][4];
        #pragma unroll
        for (int m = 0; m < 2; ++m)
            #pragma unroll
            for (int n = 0; n < 4; ++n)
                #pragma unroll
                for (int r = 0; r < 4; ++r) acc1[m][n][r] = b1c[n];

        #pragma unroll
        for (int ks = 0; ks < 16; ++ks) {
            // W1 phase (ring slot 0)
            stage4(pW + (size_t)cur * SLICE_B, ring + (cur & 1) * SLICE_B, wv, lane);
            cur = (cur == NSLICE - 1) ? 0 : cur + 1;
            VM_SYNC();
            if (ks == 0) {
                #pragma unroll
                for (int m = 0; m < 2; ++m)
                    #pragma unroll
                    for (int n = 0; n < 4; ++n)
                        #pragma unroll
                        for (int r = 0; r < 4; ++r) {
                            int row = m * 16 + q * 4 + r;
                            int col = wv * 64 + n * 16 + ln;
                            *(unsigned short*)(h0b + ((row * 1024 + col * 2) ^ ((row & 7) << 4)))
                                = f2bf(th0[m][n][r]);
                        }
                LG_SYNC();
            }
            {
                char* rs = ring;   // slot 0
                short8 bfr[4];
                #pragma unroll
                for (int n = 0; n < 4; ++n)
                    bfr[n] = *(const short8*)(rs + ((wv * 4 + n) * 64 + lane) * 16);
                #pragma unroll
                for (int m = 0; m < 2; ++m) {
                    short8 aw = *(const short8*)(h0b + (((m * 16 + ln) * 1024 + ks * 64 + q * 16) ^ swz));
                    #pragma unroll
                    for (int n = 0; n < 4; ++n)
                        acc1[m][n] = __builtin_amdgcn_mfma_f32_16x16x32_bf16(aw, bfr[n], acc1[m][n], 0, 0, 0);
                }
            }
            // U1 phase (ring slot 1)
            stage4(pW + (size_t)cur * SLICE_B, ring + (cur & 1) * SLICE_B, wv, lane);
            cur = (cur == NSLICE - 1) ? 0 : cur + 1;
            VM_SYNC();
            {
                char* rs = ring + SLICE_B;   // slot 1
                short8 bfr[4];
                #pragma unroll
                for (int n = 0; n < 4; ++n)
                    bfr[n] = *(const short8*)(rs + ((wv * 4 + n) * 64 + lane) * 16);
                #pragma unroll
                for (int m = 0; m < 2; ++m) {
                    short8 au = *(const short8*)(h1b + (((m * 16 + ln) * 1024 + ks * 64 + q * 16) ^ swz));
                    #pragma unroll
                    for (int n = 0; n < 4; ++n)
                        acc1[m][n] = __builtin_amdgcn_mfma_f32_16x16x32_bf16(au, bfr[n], acc1[m][n], 0, 0, 0);
                }
            }
        }

        #pragma unroll
        for (int m = 0; m < 2; ++m)
            #pragma unroll
            for (int n = 0; n < 4; ++n)
                #pragma unroll
                for (int r = 0; r < 4; ++r) th1[m][n][r] = tanhf(acc1[m][n][r]);
    }

    // ---------------- epilogue ----------------
    asm volatile("s_waitcnt vmcnt(0) lgkmcnt(0)" ::: "memory");
    __builtin_amdgcn_sched_barrier(0);
    __builtin_amdgcn_s_barrier();
    __builtin_amdgcn_sched_barrier(0);

    #pragma unroll
    for (int m = 0; m < 2; ++m)
        #pragma unroll
        for (int n = 0; n < 4; ++n)
            #pragma unroll
            for (int r = 0; r < 4; ++r)
                finalb[(m * 16 + q * 4 + r) * Uu + wv * 64 + n * 16 + ln] = th1[m][n][r];
    LG_SYNC();

    // out[row] = sigmoid(h1[row,:] @ Wout + bout); wave wv -> rows wv*4 .. wv*4+3
    #pragma unroll
    for (int rr = 0; rr < 4; ++rr) {
        int row = wv * 4 + rr;
        float s = 0.f;
        #pragma unroll
        for (int j = 0; j < 8; ++j)
            s += finalb[row * Uu + lane * 8 + j] * wout[j];
        #pragma unroll
        for (int off = 32; off; off >>= 1) s += __shfl_xor(s, off);
        if (lane == 0) out[bbase + row] = 1.f / (1.f + expf(-(s + boutv)));
    }
}

extern "C" void kernel_launch(void* const* d_in, const int* in_sizes, int n_in,
                              void* d_out, int out_size, void* d_ws, size_t ws_size,
                              hipStream_t stream) {
    const int*   tokens = (const int*)d_in[0];
    const float* emb    = (const float*)d_in[1];
    const float* W0     = (const float*)d_in[2];
    const float* U0     = (const float*)d_in[3];
    const float* b0     = (const float*)d_in[4];
    const float* W1     = (const float*)d_in[5];
    const float* U1     = (const float*)d_in[6];
    const float* b1     = (const float*)d_in[7];
    const float* Wout   = (const float*)d_in[8];
    const float* bout   = (const float*)d_in[9];
    float* outp = (float*)d_out;

    char* ws = (char*)d_ws;
    float* embW0 = (float*)ws;                                   // 20,480,000 B
    unsigned short* pW = (unsigned short*)(ws + 20480000);       // 48 * 32KB = 1.5MB

    hipLaunchKernelGGL(k_embw0, dim3(Vv / 4), dim3(512), 0, stream, emb, W0, b0, embW0);
    hipLaunchKernelGGL(k_pack, dim3(384), dim3(256), 0, stream, U0, W1, U1, pW);
    hipLaunchKernelGGL(k_rnn, dim3(NBLK), dim3(512), 0, stream,
                       tokens, embW0, pW, b1, Wout, bout, outp);
}